// Round 15
// baseline (106.794 us; speedup 1.0000x reference)
//
#include <hip/hip_runtime.h>
#include <math.h>

// ---------------------------------------------------------------------------
// AngleEncodingQuantumNet: conv1+BN+relu+pool -> conv2+BN+relu+pool -> fc1
// (tanh) -> sel -> 10-qubit RY/CZ circuit -> post1(relu) -> post2.
// R15 = R13 (tail reverted from R14's 2-wave split: prediction failed) +
// pack_a ELIMINATED: pooled stored in hv order [m][oc*49+quad]; fc1's
// A-staging applies BN2+relu+hi/lo bf16 split on the fly from pooled+stats2
// (oc via exact magic (i*1338)>>16). K-steps 52->49 (pad gone; split-K
// quarters 13/13/13/10). Pipeline: conv1_stats -> bnstat -> conv2(conv1-
// fused MFMA, pooled-select) -> bnstat -> fc1 -> tail.  absmax ~7.6e-6.
// ---------------------------------------------------------------------------

#define BATCH 2048
#define PI_F 3.14159265358979323846f
#define KP 3328          // fc1 B row stride (ushorts); only [0,3136) read
#define BSTR2 312        // conv2 B' row stride (ushorts): 18 sec + zero pad
#define AROW 392         // conv2 aT 16-pixel row stride (ushorts): bank step 4
#define APLANE 6272      // 16 * AROW
#define AIMG 12544       // 2 * APLANE

typedef unsigned short ushort_t;
typedef __attribute__((ext_vector_type(8))) short bf16x8;
typedef __attribute__((ext_vector_type(4))) float f32x4;

__device__ __forceinline__ float wave_reduce_add(float v) {
#pragma unroll
  for (int off = 32; off >= 1; off >>= 1) v += __shfl_xor(v, off, 64);
  return v;
}

__device__ __forceinline__ ushort_t f2bf(float v) {  // RNE f32 -> bf16 bits
  unsigned u = __float_as_uint(v);
  u += 0x7FFFu + ((u >> 16) & 1u);
  return (ushort_t)(u >> 16);
}
__device__ __forceinline__ float bf2f(ushort_t b) {
  return __uint_as_float(((unsigned)b) << 16);
}

__device__ __forceinline__ float tanh_fast(float x) {  // overflow-safe, ~1e-7
  float e = __expf(-2.f * fabsf(x));
  float r = (1.f - e) / (1.f + e);
  return copysignf(r, x);
}

// BN2+relu+split transform for one staged uint4 (8 elems); i0 = hv index of
// elem 0; lo selects the residual half. oc=(i*1338)>>16 == i/49 for i<1568.
__device__ __forceinline__ uint4 xformA(float4 fa, float4 fb, int i0, bool lo,
                                        const float* __restrict__ st2) {
  float f[8] = {fa.x, fa.y, fa.z, fa.w, fb.x, fb.y, fb.z, fb.w};
  union { ushort_t u[8]; uint4 v; } o;
#pragma unroll
  for (int j = 0; j < 8; ++j) {
    int oc = ((i0 + j) * 1338) >> 16;
    float hv = fmaxf(fmaf(st2[oc * 2], f[j], st2[oc * 2 + 1]), 0.f);
    ushort_t hi = f2bf(hv);
    o.u[j] = lo ? f2bf(hv - bf2f(hi)) : hi;
  }
  return o.v;
}

// ---------------- conv1: stats pass (+ bonus blocks: conv2 B', fc1 B') -----
__global__ __launch_bounds__(256) void k_conv1_stats(
    const float* __restrict__ x, const float* __restrict__ cw,
    const float* __restrict__ cb, float* __restrict__ part1,
    const float* __restrict__ cw2, ushort_t* __restrict__ wB,
    const float* __restrict__ fc1w, ushort_t* __restrict__ Bp) {
  const int t = threadIdx.x;
  if (blockIdx.x >= BATCH) {
    const int bid = blockIdx.x - BATCH;
    if (bid == 0) {
      // conv2 B': [oc][k2], k2 = sec*16+ic; sec 0..8 = Bh, 9..17 = Bl, pad 0
      for (int i = t; i < 32 * BSTR2; i += 256) {
        int oc = i / BSTR2, k = i - oc * BSTR2;
        ushort_t val = 0;
        if (k < 288) {
          int sec2 = k >> 4, ic = k & 15;
          if (sec2 < 9) {
            val = f2bf(cw2[oc * 144 + ic * 9 + sec2]);
          } else {
            float w = cw2[oc * 144 + ic * 9 + (sec2 - 9)];
            val = f2bf(w - bf2f(f2bf(w)));
          }
        }
        wB[i] = val;
      }
    } else {
      // fc1 B': [Bh | Bh] bf16, 896 rows x KP (rows>=784 and tail zeros)
      const int rb = (bid - 1) * 8;
      for (int i = t; i < 8 * (KP / 8); i += 256) {
        int rr = i / (KP / 8), c = i - rr * (KP / 8);
        int n = rb + rr;
        union { ushort_t u[8]; uint4 v; } o;
        o.v = make_uint4(0, 0, 0, 0);
        if (n < 784 && c < 392) {
          int cc = c < 196 ? c : c - 196;
          const float* wp = fc1w + (size_t)n * 1568 + cc * 8;
#pragma unroll
          for (int j = 0; j < 8; ++j) o.u[j] = f2bf(wp[j]);
        }
        ((uint4*)(Bp + (size_t)n * KP))[c] = o.v;
      }
    }
    return;
  }
  const int b = blockIdx.x;
  __shared__ float xs[30][33];
  __shared__ float ws[160];
  __shared__ float redS[16][28];
  __shared__ float redQ[16][28];
  for (int i = t; i < 30 * 33; i += 256) (&xs[0][0])[i] = 0.f;
  if (t < 144) ws[t] = cw[t];
  else if (t < 160) ws[t] = cb[t - 144];
  __syncthreads();
  const float* xb = x + b * 784;
  for (int i = t; i < 784; i += 256) xs[1 + i / 28][1 + (i % 28)] = xb[i];
  __syncthreads();
  for (int task = t; task < 448; task += 256) {
    const int oc = task / 28;
    const int row = task - oc * 28;
    float wk[9];
#pragma unroll
    for (int k = 0; k < 9; ++k) wk[k] = ws[oc * 9 + k];
    const float bc = ws[144 + oc];
    float A0 = xs[row][0], A1 = xs[row][1];
    float B0 = xs[row + 1][0], B1 = xs[row + 1][1];
    float C0 = xs[row + 2][0], C1 = xs[row + 2][1];
    float s = 0.f, q = 0.f;
#pragma unroll 4
    for (int xx = 0; xx < 28; ++xx) {
      float A2 = xs[row][xx + 2], B2 = xs[row + 1][xx + 2], C2 = xs[row + 2][xx + 2];
      float acc = bc;
      acc = fmaf(wk[0], A0, acc); acc = fmaf(wk[1], A1, acc); acc = fmaf(wk[2], A2, acc);
      acc = fmaf(wk[3], B0, acc); acc = fmaf(wk[4], B1, acc); acc = fmaf(wk[5], B2, acc);
      acc = fmaf(wk[6], C0, acc); acc = fmaf(wk[7], C1, acc); acc = fmaf(wk[8], C2, acc);
      s += acc; q = fmaf(acc, acc, q);
      A0 = A1; A1 = A2; B0 = B1; B1 = B2; C0 = C1; C1 = C2;
    }
    redS[oc][row] = s;
    redQ[oc][row] = q;
  }
  __syncthreads();
  if (t < 32) {
    const int c = t >> 1;
    float acc = 0.f;
    if (t & 1) {
#pragma unroll 4
      for (int r = 0; r < 28; ++r) acc += redQ[c][r];
    } else {
#pragma unroll 4
      for (int r = 0; r < 28; ++r) acc += redS[c][r];
    }
    part1[b * 32 + t] = acc;
  }
}

// ---------------- BN stats fold (both layers) -------------------------------
__global__ __launch_bounds__(256) void k_bnstat(
    const float* __restrict__ part, const float* __restrict__ g,
    const float* __restrict__ bb, float* __restrict__ stats,
    int nch, int nblk, double invN) {
  const int c = blockIdx.x;
  const int t = threadIdx.x;
  const int stride = nch * 2;
  double ls = 0.0, lq = 0.0;
  for (int i = t; i < nblk; i += 256) {
    ls += (double)part[i * stride + c * 2];
    lq += (double)part[i * stride + c * 2 + 1];
  }
#pragma unroll
  for (int off = 32; off >= 1; off >>= 1) {
    ls += __shfl_xor(ls, off, 64);
    lq += __shfl_xor(lq, off, 64);
  }
  __shared__ double rs[4], rq[4];
  if ((t & 63) == 0) { rs[t >> 6] = ls; rq[t >> 6] = lq; }
  __syncthreads();
  if (t == 0) {
    double S = rs[0] + rs[1] + rs[2] + rs[3];
    double Q = rq[0] + rq[1] + rq[2] + rq[3];
    double mean = S * invN;
    double var = Q * invN - mean * mean;
    double inv = 1.0 / sqrt(var + 1e-5);
    double sc = (double)g[c] * inv;
    stats[c * 2] = (float)sc;
    stats[c * 2 + 1] = (float)((double)bb[c] - mean * sc);
  }
}

// ---------------- conv1(fused)+conv2 via MFMA, pooled select by sign(g2) ----
// pooled layout (hv order): pooled[m][oc*49+quad]
__global__ __launch_bounds__(512, 2) void k_conv2_mfma(
    const float* __restrict__ x, const float* __restrict__ cw1,
    const float* __restrict__ cb1, const float* __restrict__ stats1,
    const ushort_t* __restrict__ wB, const float* __restrict__ cb,
    const float* __restrict__ g2, float* __restrict__ part2,
    float* __restrict__ pooled) {
  const int b0 = blockIdx.x * 2;
  const int t = threadIdx.x;
  __shared__ __align__(16) ushort_t aT[2 * AIMG];     // 50,176 B
  __shared__ __align__(16) ushort_t bS[32 * BSTR2];   // 19,968 B
  __shared__ float xs[2][30][33];                     //  7,920 B
  __shared__ float wsc[160];                          //    640 B
  __shared__ float red[2][4][64];                     //  2,048 B
  {
    uint4 z = make_uint4(0, 0, 0, 0);
    uint4* a4 = (uint4*)aT;
    for (int i = t; i < (2 * AIMG) / 8; i += 512) a4[i] = z;
    float4* xz = (float4*)&xs[0][0][0];
    if (t < 495) xz[t] = make_float4(0.f, 0.f, 0.f, 0.f);
    if (t < 160) wsc[t] = (t < 144) ? cw1[t] : cb1[t - 144];
    uint4* b4 = (uint4*)bS;
    const uint4* w4 = (const uint4*)wB;
    for (int i = t; i < (32 * BSTR2) / 8; i += 512) b4[i] = w4[i];
  }
  __syncthreads();
  {
    const float* xb = x + (size_t)b0 * 784;
    for (int i = t; i < 1568; i += 512) {
      int img = i / 784, j = i - img * 784;
      xs[img][1 + j / 28][1 + (j % 28)] = xb[img * 784 + j];
    }
  }
  __syncthreads();
  // ---- conv1 + BN1 + relu + 2x2 pool, hi/lo split -> aT ----
  if (t < 448) {
    const int img = t / 224, tt = t - img * 224;
    const int oc = tt / 14, pr = tt - oc * 14;
    float wk[9];
#pragma unroll
    for (int k = 0; k < 9; ++k) wk[k] = wsc[oc * 9 + k];
    const float bc = wsc[144 + oc];
    const float scale = stats1[oc * 2], shift = stats1[oc * 2 + 1];
    const int r0 = 2 * pr;
    float A0 = xs[img][r0][0],     A1 = xs[img][r0][1];
    float B0 = xs[img][r0 + 1][0], B1 = xs[img][r0 + 1][1];
    float C0 = xs[img][r0 + 2][0], C1 = xs[img][r0 + 2][1];
    float D0 = xs[img][r0 + 3][0], D1 = xs[img][r0 + 3][1];
    float pmax = 0.f;
#pragma unroll 4
    for (int xx = 0; xx < 28; ++xx) {
      float A2 = xs[img][r0][xx + 2], B2 = xs[img][r0 + 1][xx + 2];
      float C2 = xs[img][r0 + 2][xx + 2], D2 = xs[img][r0 + 3][xx + 2];
      float c0 = bc, c1 = bc;
      c0 = fmaf(wk[0], A0, c0); c0 = fmaf(wk[1], A1, c0); c0 = fmaf(wk[2], A2, c0);
      c0 = fmaf(wk[3], B0, c0); c0 = fmaf(wk[4], B1, c0); c0 = fmaf(wk[5], B2, c0);
      c0 = fmaf(wk[6], C0, c0); c0 = fmaf(wk[7], C1, c0); c0 = fmaf(wk[8], C2, c0);
      c1 = fmaf(wk[0], B0, c1); c1 = fmaf(wk[1], B1, c1); c1 = fmaf(wk[2], B2, c1);
      c1 = fmaf(wk[3], C0, c1); c1 = fmaf(wk[4], C1, c1); c1 = fmaf(wk[5], C2, c1);
      c1 = fmaf(wk[6], D0, c1); c1 = fmaf(wk[7], D1, c1); c1 = fmaf(wk[8], D2, c1);
      float e0 = fmaxf(fmaf(scale, c0, shift), 0.f);
      float e1 = fmaxf(fmaf(scale, c1, shift), 0.f);
      float m = fmaxf(e0, e1);
      if ((xx & 1) == 0) {
        pmax = m;
      } else {
        float pv = fmaxf(pmax, m);
        ushort_t hi = f2bf(pv);
        ushort_t lo = f2bf(pv - bf2f(hi));
        int off = img * AIMG + (pr + 1) * AROW + ((xx >> 1) + 1) * 24 + oc;
        aT[off] = hi;
        aT[off + APLANE] = lo;
      }
      A0 = A1; A1 = A2; B0 = B1; B1 = B2; C0 = C1; C1 = C2; D0 = D1; D1 = D2;
    }
  }
  __syncthreads();

  // ---- conv2 MFMA ----
  const int lane = t & 63;
  const int wv = t >> 6;
  const int img = wv >> 2, wi = wv & 3;
  const int ic0 = ((lane >> 4) & 1) * 8;
  const int hb = lane >> 5;
  const int imgbase = img * AIMG;
  int abase[4];
#pragma unroll
  for (int fi = 0; fi < 4; ++fi) {
    int f = wi + fi * 4;
    int pp = f * 16 + (lane & 15);       // quad-major row index
    int quad = pp >> 2;
    if (quad > 48) quad = 48;            // clamp: keeps A-read in-bounds
    int corner = pp & 3;
    int qy = quad / 7, qx = quad - qy * 7;
    int y = 2 * qy + (corner >> 1), xq = 2 * qx + (corner & 1);
    abase[fi] = imgbase + y * AROW + xq * 24 + ic0;  // output coords, no +1
  }
  f32x4 acc[4][2];
  {
    const float bias0 = cb[lane & 15];
    const float bias1 = cb[16 + (lane & 15)];
#pragma unroll
    for (int fi = 0; fi < 4; ++fi) {
      acc[fi][0] = (f32x4){bias0, bias0, bias0, bias0};
      acc[fi][1] = (f32x4){bias1, bias1, bias1, bias1};
    }
  }
  const int brow = (lane & 15) * BSTR2 + ic0;
#pragma unroll
  for (int kt = 0; kt < 14; ++kt) {
    int sec = 2 * kt + hb;
    int ss = sec >= 18 ? sec - 18 : (sec >= 9 ? sec - 9 : sec);
    int col16;                       // deduped B column (16-wide sections)
    if (sec >= 27) { ss = 8; col16 = 18; }      // zero pad
    else if (sec >= 18) col16 = 9 + ss;          // Bl
    else col16 = ss;                             // Bh (sec 0..17)
    int plane = (sec >= 9 && sec < 18) ? 1 : 0;
    bf16x8 bv0 = *(const bf16x8*)&bS[brow + col16 * 16];
    bf16x8 bv1 = *(const bf16x8*)&bS[brow + 16 * BSTR2 + col16 * 16];
    int dy = ss / 3, dx = ss - dy * 3;
    int doff = plane * APLANE + dy * AROW + dx * 24;
#pragma unroll
    for (int fi = 0; fi < 4; ++fi) {
      if (wi + fi * 4 < 13) {
        bf16x8 av = *(const bf16x8*)&aT[doff + abase[fi]];
        acc[fi][0] = __builtin_amdgcn_mfma_f32_16x16x32_bf16(av, bv0, acc[fi][0], 0, 0, 0);
        acc[fi][1] = __builtin_amdgcn_mfma_f32_16x16x32_bf16(av, bv1, acc[fi][1], 0, 0, 0);
      }
    }
  }
  // epilogue: in-lane 2x2 pool; keep max if g2>=0 else min (BN monotone);
  // pooled in hv order: [oc*49 + quad]
  const float gs0 = g2[lane & 15];
  const float gs1 = g2[16 + (lane & 15)];
  float s0 = 0.f, q0 = 0.f, s1 = 0.f, q1 = 0.f;
  float* pm = pooled + (size_t)(b0 + img) * 1568;
#pragma unroll
  for (int fi = 0; fi < 4; ++fi) {
    int f = wi + fi * 4;
    int quad = f * 4 + (lane >> 4);
    if (quad < 49) {
      f32x4 a0 = acc[fi][0], a1 = acc[fi][1];
#pragma unroll
      for (int r = 0; r < 4; ++r) {
        s0 += a0[r]; q0 = fmaf(a0[r], a0[r], q0);
        s1 += a1[r]; q1 = fmaf(a1[r], a1[r], q1);
      }
      float mx0 = fmaxf(fmaxf(a0[0], a0[1]), fmaxf(a0[2], a0[3]));
      float mn0 = fminf(fminf(a0[0], a0[1]), fminf(a0[2], a0[3]));
      float mx1 = fmaxf(fmaxf(a1[0], a1[1]), fmaxf(a1[2], a1[3]));
      float mn1 = fminf(fminf(a1[0], a1[1]), fminf(a1[2], a1[3]));
      pm[(lane & 15) * 49 + quad] = (gs0 >= 0.f) ? mx0 : mn0;
      pm[(16 + (lane & 15)) * 49 + quad] = (gs1 >= 0.f) ? mx1 : mn1;
    }
  }
  s0 += __shfl_xor(s0, 16, 64); s0 += __shfl_xor(s0, 32, 64);
  q0 += __shfl_xor(q0, 16, 64); q0 += __shfl_xor(q0, 32, 64);
  s1 += __shfl_xor(s1, 16, 64); s1 += __shfl_xor(s1, 32, 64);
  q1 += __shfl_xor(q1, 16, 64); q1 += __shfl_xor(q1, 32, 64);
  if (lane < 16) {
    red[img][wi][lane * 2] = s0;        red[img][wi][lane * 2 + 1] = q0;
    red[img][wi][(lane + 16) * 2] = s1; red[img][wi][(lane + 16) * 2 + 1] = q1;
  }
  __syncthreads();
  if (t < 128) {
    int im = t >> 6, c = t & 63;
    part2[(b0 + im) * 64 + c] =
        red[im][0][c] + red[im][1][c] + red[im][2][c] + red[im][3][c];
  }
}

// ---------------- fc1 bf16 MFMA GEMM: 128x128 tile, split-K 13/13/13/10 -----
// A staged DIRECTLY from pooled (hv order) + stats2: BN2+relu+bf16 split in
// the staging path (bit-identical to the old pack_a). 49 K-steps total.
__global__ __launch_bounds__(512, 2) void k_fc1_mfma(
    const float* __restrict__ pooled, const float* __restrict__ stats2,
    const ushort_t* __restrict__ Bp, float* __restrict__ partial) {
  __shared__ ushort_t As[128 * 64];
  __shared__ ushort_t Bs[128 * 64];
  __shared__ float st2[64];
  const int t = threadIdx.x;
  if (t < 64) st2[t] = stats2[t];
  const int id = blockIdx.x;
  const int xcd = id & 7, w = id >> 3;           // w in 0..55
  const int mtl = w / 28, rem = w - mtl * 28;
  const int ks = rem / 7, nt = rem - ks * 7;
  const int mt = xcd * 2 + mtl;
  const int m0 = mt * 128, n0 = nt * 128;
  const int lane = t & 63, wid = t >> 6;
  const int wm = wid >> 2, wn = wid & 3;

  const int srow = t >> 3, sslot = t & 7;
  const int xsl = (sslot ^ (srow & 7)) << 3;
  ushort_t* awp = &As[srow * 64 + xsl];
  ushort_t* bwp = &Bs[srow * 64 + xsl];
  const float* prow0 = pooled + (size_t)(m0 + srow) * 1568;
  const float* prow1 = prow0 + (size_t)64 * 1568;
  const uint4* bgp = (const uint4*)(Bp + (size_t)(n0 + srow) * KP) + sslot;
  const int ROWOFF = 64 * (KP / 8);

  const int rbaseA = (wm * 64 + (lane & 15)) * 64;
  const int rbaseB = (wn * 32 + (lane & 15)) * 64;
  const int x0 = ((lane >> 4) ^ (lane & 7)) << 3;
  const int x1 = (((lane >> 4) + 4) ^ (lane & 7)) << 3;

  f32x4 acc[4][2];
#pragma unroll
  for (int fm = 0; fm < 4; ++fm) {
    acc[fm][0] = (f32x4){0.f, 0.f, 0.f, 0.f};
    acc[fm][1] = (f32x4){0.f, 0.f, 0.f, 0.f};
  }
  const int kt0 = ks * 13;
  const int ktEnd = (ks == 3) ? 49 : kt0 + 13;

  // prefetch step kt0
  float4 fa00, fa01, fa10, fa11;
  uint4 cb0, cb1;
  {
    int c = kt0 * 64 + sslot * 8;
    int ci = (c < 1568) ? c : c - 1568;
    fa00 = *(const float4*)(prow0 + ci);
    fa01 = *(const float4*)(prow0 + ci + 4);
    fa10 = *(const float4*)(prow1 + ci);
    fa11 = *(const float4*)(prow1 + ci + 4);
    cb0 = bgp[kt0 * 8];
    cb1 = bgp[kt0 * 8 + ROWOFF];
  }
  for (int kt = kt0; kt < ktEnd; ++kt) {
    const int c = kt * 64 + sslot * 8;
    const bool lo = c >= 1568;
    const int i0 = lo ? c - 1568 : c;
    __syncthreads();
    *(uint4*)awp = xformA(fa00, fa01, i0, lo, st2);
    *(uint4*)(awp + 64 * 64) = xformA(fa10, fa11, i0, lo, st2);
    *(uint4*)bwp = cb0;
    *(uint4*)(bwp + 64 * 64) = cb1;
    __syncthreads();
    if (kt + 1 < ktEnd) {  // prefetch next step; MFMA hides latency
      int cn = (kt + 1) * 64 + sslot * 8;
      int cin = (cn < 1568) ? cn : cn - 1568;
      fa00 = *(const float4*)(prow0 + cin);
      fa01 = *(const float4*)(prow0 + cin + 4);
      fa10 = *(const float4*)(prow1 + cin);
      fa11 = *(const float4*)(prow1 + cin + 4);
      cb0 = bgp[(kt + 1) * 8];
      cb1 = bgp[(kt + 1) * 8 + ROWOFF];
    }
#pragma unroll
    for (int kh = 0; kh < 2; ++kh) {
      const int xx = kh ? x1 : x0;
      bf16x8 b0 = *(const bf16x8*)&Bs[rbaseB + xx];
      bf16x8 b1 = *(const bf16x8*)&Bs[rbaseB + 16 * 64 + xx];
#pragma unroll
      for (int fm = 0; fm < 4; ++fm) {
        bf16x8 a = *(const bf16x8*)&As[rbaseA + fm * 1024 + xx];
        acc[fm][0] = __builtin_amdgcn_mfma_f32_16x16x32_bf16(a, b0, acc[fm][0], 0, 0, 0);
        acc[fm][1] = __builtin_amdgcn_mfma_f32_16x16x32_bf16(a, b1, acc[fm][1], 0, 0, 0);
      }
    }
  }
  // C/D: col=lane&15, row=(lane>>4)*4+reg [m89]; partial [ks][2048][832]
  const int mrow0 = m0 + wm * 64 + ((lane >> 4) << 2);
  const int col0 = n0 + wn * 32 + (lane & 15);
#pragma unroll
  for (int fm = 0; fm < 4; ++fm) {
#pragma unroll
    for (int fn = 0; fn < 2; ++fn) {
      int col = col0 + fn * 16;
      if (col < 832) {
        float* pb = partial + ((size_t)ks * 2048 + mrow0 + fm * 16) * 832 + col;
#pragma unroll
        for (int r = 0; r < 4; ++r) pb[(size_t)r * 832] = acc[fm][fn][r];
      }
    }
  }
}

// ---------------- quantum gate helper (value-passed cos/sin) ----------------
template <int W>
__device__ __forceinline__ void ry_cs(float (&a)[16], int lane, float c, float s) {
  if (W < 4) {
    const int st = 1 << W;
#pragma unroll
    for (int r = 0; r < 16; ++r) {
      if (!(r & st)) {
        float lo = a[r], hi = a[r + st];
        a[r] = fmaf(c, lo, -s * hi);
        a[r + st] = fmaf(s, lo, c * hi);
      }
    }
  } else {
    const int m = 1 << (W - 4);
    const float sg = (lane & m) ? s : -s;
#pragma unroll
    for (int r = 0; r < 16; ++r) {
      float other = __shfl_xor(a[r], m, 64);
      a[r] = fmaf(c, a[r], sg * other);
    }
  }
}

#define RYCS(GC, GS)                                                  \
  {                                                                   \
    ry_cs<0>(a, lane, GC(0), GS(0)); ry_cs<1>(a, lane, GC(1), GS(1)); \
    ry_cs<2>(a, lane, GC(2), GS(2)); ry_cs<3>(a, lane, GC(3), GS(3)); \
    ry_cs<4>(a, lane, GC(4), GS(4)); ry_cs<5>(a, lane, GC(5), GS(5)); \
    ry_cs<6>(a, lane, GC(6), GS(6)); ry_cs<7>(a, lane, GC(7), GS(7)); \
    ry_cs<8>(a, lane, GC(8), GS(8)); ry_cs<9>(a, lane, GC(9), GS(9)); \
  }

// ---------------- fused tail: combine + sel + quantum + post ----------------
// Circuit algebra: encoding RY and layer-0 RY merge into a product state.
__global__ __launch_bounds__(256) void k_tail(
    const float* __restrict__ partial, const float* __restrict__ fb,
    const float* __restrict__ sw, const float* __restrict__ sb,
    const float* __restrict__ qp, const float* __restrict__ w1,
    const float* __restrict__ b1, const float* __restrict__ w2,
    const float* __restrict__ b2, float* __restrict__ out) {
  const int t = threadIdx.x;
  __shared__ __align__(16) float swL[7840];
  __shared__ float lc[30], ls[30];
  __shared__ float hbuf[4][32];
  {
    const float4* swg = (const float4*)sw;
    float4* swd = (float4*)swL;
    for (int i = t; i < 1960; i += 256) swd[i] = swg[i];
  }
  if (t < 30) {   // layers 1,2 used as (cos,sin)
    float th = 0.5f * qp[t];
    lc[t] = __cosf(th);
    ls[t] = __sinf(th);
  }
  __syncthreads();
  const int wv = t >> 6;
  const int m = blockIdx.x * 4 + wv;
  const int lane = t & 63;

  const float4* p4 = (const float4*)(partial + (size_t)m * 832);
  const size_t KSL4 = (size_t)2048 * 832 / 4;
  const float4* fb4 = (const float4*)fb;
  const float4* sw4 = (const float4*)swL;
  float acc[10];
#pragma unroll
  for (int i = 0; i < 10; ++i) acc[i] = 0.f;
  for (int c4 = lane; c4 < 196; c4 += 64) {
    float4 v0 = p4[c4];
    float4 v1 = p4[c4 + KSL4];
    float4 v2 = p4[c4 + 2 * KSL4];
    float4 v3 = p4[c4 + 3 * KSL4];
    float4 bb = fb4[c4];
    float t0 = tanh_fast(v0.x + v1.x + v2.x + v3.x + bb.x);
    float t1 = tanh_fast(v0.y + v1.y + v2.y + v3.y + bb.y);
    float t2 = tanh_fast(v0.z + v1.z + v2.z + v3.z + bb.z);
    float t3 = tanh_fast(v0.w + v1.w + v2.w + v3.w + bb.w);
#pragma unroll
    for (int i = 0; i < 10; ++i) {
      float4 w = sw4[i * 196 + c4];
      acc[i] = fmaf(t0, w.x, acc[i]);
      acc[i] = fmaf(t1, w.y, acc[i]);
      acc[i] = fmaf(t2, w.z, acc[i]);
      acc[i] = fmaf(t3, w.w, acc[i]);
    }
  }
#pragma unroll
  for (int i = 0; i < 10; ++i) acc[i] = wave_reduce_add(acc[i]) + sb[i];

  // ---- product state (encoding + layer-0 RY merged) ----
  float pc[10], psn[10];
#pragma unroll
  for (int i = 0; i < 10; ++i) {
    float h = fmaf(acc[i], 0.5f * PI_F, 0.5f * qp[i]);
    pc[i] = __cosf(h);
    psn[i] = __sinf(h);
  }
  float p01[4] = {pc[0] * pc[1], psn[0] * pc[1], pc[0] * psn[1], psn[0] * psn[1]};
  float p23[4] = {pc[2] * pc[3], psn[2] * pc[3], pc[2] * psn[3], psn[2] * psn[3]};
  float L = (lane & 1) ? psn[4] : pc[4];
  L *= ((lane >> 1) & 1) ? psn[5] : pc[5];
  L *= ((lane >> 2) & 1) ? psn[6] : pc[6];
  L *= ((lane >> 3) & 1) ? psn[7] : pc[7];
  L *= ((lane >> 4) & 1) ? psn[8] : pc[8];
  L *= ((lane >> 5) & 1) ? psn[9] : pc[9];
  float a[16];
#pragma unroll
  for (int r = 0; r < 16; ++r) a[r] = L * p01[r & 3] * p23[r >> 2];

  float czs[16];
#pragma unroll
  for (int r = 0; r < 16; ++r) {
    int idx = (lane << 4) | r;
    czs[r] = (__popc(idx & (idx >> 1)) & 1) ? -1.f : 1.f;
  }
  // CZ(L0) -> RY(L1) -> CZ(L1) -> RY(L2) -> CZ(L2)
#pragma unroll
  for (int r = 0; r < 16; ++r) a[r] *= czs[r];
#pragma unroll
  for (int layer = 1; layer < 3; ++layer) {
    const int lb = layer * 10;
#define LC(i) (lc[lb + i])
#define LS(i) (ls[lb + i])
    RYCS(LC, LS)
#undef LC
#undef LS
#pragma unroll
    for (int r = 0; r < 16; ++r) a[r] *= czs[r];
  }
  float p[16];
  float lt = 0.f;
#pragma unroll
  for (int r = 0; r < 16; ++r) { p[r] = a[r] * a[r]; lt += p[r]; }
  float z[10];
#pragma unroll
  for (int ww = 0; ww < 4; ++ww) {
    float v = 0.f;
#pragma unroll
    for (int r = 0; r < 16; ++r) v += ((r >> ww) & 1) ? -p[r] : p[r];
    z[ww] = v;
  }
#pragma unroll
  for (int ww = 4; ww < 10; ++ww) z[ww] = ((lane >> (ww - 4)) & 1) ? -lt : lt;
#pragma unroll
  for (int ww = 0; ww < 10; ++ww) z[ww] = wave_reduce_add(z[ww]);

  if (lane < 32) {
    float s = b1[lane];
#pragma unroll
    for (int i = 0; i < 10; ++i) s = fmaf(w1[lane * 10 + i], z[i], s);
    hbuf[wv][lane] = fmaxf(s, 0.f);
  }
  __syncthreads();
  if (lane < 10) {
    float s = b2[lane];
#pragma unroll
    for (int jj = 0; jj < 32; ++jj) s = fmaf(w2[lane * 32 + jj], hbuf[wv][jj], s);
    out[m * 10 + lane] = s;
  }
}

// ---------------------------------------------------------------------------
extern "C" void kernel_launch(void* const* d_in, const int* in_sizes, int n_in,
                              void* d_out, int out_size, void* d_ws, size_t ws_size,
                              hipStream_t stream) {
  (void)in_sizes; (void)n_in; (void)out_size; (void)ws_size;
  const float* x    = (const float*)d_in[0];
  const float* c1w  = (const float*)d_in[1];
  const float* c1b  = (const float*)d_in[2];
  const float* bn1g = (const float*)d_in[3];
  const float* bn1b = (const float*)d_in[4];
  const float* c2w  = (const float*)d_in[5];
  const float* c2b  = (const float*)d_in[6];
  const float* bn2g = (const float*)d_in[7];
  const float* bn2b = (const float*)d_in[8];
  const float* fc1w = (const float*)d_in[9];
  const float* fc1b = (const float*)d_in[10];
  const float* selw = (const float*)d_in[11];
  const float* selb = (const float*)d_in[12];
  const float* qpar = (const float*)d_in[13];
  const float* p1w  = (const float*)d_in[14];
  const float* p1b  = (const float*)d_in[15];
  const float* p2w  = (const float*)d_in[16];
  const float* p2b  = (const float*)d_in[17];

  // ws layout (floats) — no aliases needed (~46.6 MB total, budget 89.8 MB).
  float* ws = (float*)d_ws;
  float* pooled  = ws;                      // 3,211,264 f [2048][1568] hv order
  size_t o = 3211264;
  float* partial = ws + o; o += 6815744;    // [4][2048][832]
  ushort_t* Bp  = (ushort_t*)(ws + o); o += 1490944;  // 896*3328 ushorts
  ushort_t* wB  = (ushort_t*)(ws + o); o += 4992;     // 32*312 ushorts
  float* part1  = ws + o; o += 65536;
  float* part2  = ws + o; o += 131072;
  float* stats1 = ws + o; o += 32;
  float* stats2 = ws + o; o += 64;
  float* outp   = (float*)d_out;

  k_conv1_stats<<<BATCH + 1 + 112, 256, 0, stream>>>(x, c1w, c1b, part1, c2w,
                                                     wB, fc1w, Bp);
  k_bnstat<<<16, 256, 0, stream>>>(part1, bn1g, bn1b, stats1, 16, BATCH,
                                   1.0 / (2048.0 * 784.0));
  k_conv2_mfma<<<BATCH / 2, 512, 0, stream>>>(x, c1w, c1b, stats1, wB, c2b,
                                              bn2g, part2, pooled);
  k_bnstat<<<32, 256, 0, stream>>>(part2, bn2g, bn2b, stats2, 32, BATCH,
                                   1.0 / (2048.0 * 196.0));
  k_fc1_mfma<<<448, 512, 0, stream>>>(pooled, stats2, Bp, partial);
  k_tail<<<BATCH / 4, 256, 0, stream>>>(partial, fc1b, selw, selb, qpar,
                                        p1w, p1b, p2w, p2b, outp);
}

// Round 16
// 93.312 us; speedup vs baseline: 1.1445x; 1.1445x over previous
//
#include <hip/hip_runtime.h>
#include <math.h>

// ---------------------------------------------------------------------------
// AngleEncodingQuantumNet: conv1+BN+relu+pool -> conv2+BN+relu+pool -> fc1
// (tanh) -> sel -> 10-qubit RY/CZ circuit -> post1(relu) -> post2.
// R16 = R15 with fc1's A_lo*B_hi split term DROPPED (error budget: exact fc1
// gave 4.8e-7, dropping A*B_lo gave 7.6e-6 measured; symmetric term adds
// ~7e-6 more -> predicted ~1.5e-5 vs 3.8e-5 threshold). fc1 is now a plain
// bf16 GEMM, K=1568 (25 steps, was 49): half the MFMA/LDS/B-reads, and A
// staging reads pooled ONCE (single xformA pass).
// Pipeline: conv1_stats -> bnstat -> conv2(conv1-fused MFMA, pooled-select)
// -> bnstat -> fc1 -> tail.
// ---------------------------------------------------------------------------

#define BATCH 2048
#define PI_F 3.14159265358979323846f
#define KP 3328          // fc1 B row stride (ushorts); only [0,1568) read now
#define BSTR2 312        // conv2 B' row stride (ushorts): 18 sec + zero pad
#define AROW 392         // conv2 aT 16-pixel row stride (ushorts): bank step 4
#define APLANE 6272      // 16 * AROW
#define AIMG 12544       // 2 * APLANE

typedef unsigned short ushort_t;
typedef __attribute__((ext_vector_type(8))) short bf16x8;
typedef __attribute__((ext_vector_type(4))) float f32x4;

__device__ __forceinline__ float wave_reduce_add(float v) {
#pragma unroll
  for (int off = 32; off >= 1; off >>= 1) v += __shfl_xor(v, off, 64);
  return v;
}

__device__ __forceinline__ ushort_t f2bf(float v) {  // RNE f32 -> bf16 bits
  unsigned u = __float_as_uint(v);
  u += 0x7FFFu + ((u >> 16) & 1u);
  return (ushort_t)(u >> 16);
}
__device__ __forceinline__ float bf2f(ushort_t b) {
  return __uint_as_float(((unsigned)b) << 16);
}

__device__ __forceinline__ float tanh_fast(float x) {  // overflow-safe, ~1e-7
  float e = __expf(-2.f * fabsf(x));
  float r = (1.f - e) / (1.f + e);
  return copysignf(r, x);
}

// BN2+relu+bf16 for one staged uint4 (8 elems); i0 = hv index of elem 0.
// oc = (i*1338)>>16 == i/49 for i < 1568 (HW-verified in R15).
__device__ __forceinline__ uint4 xformA(float4 fa, float4 fb, int i0,
                                        const float* __restrict__ st2) {
  float f[8] = {fa.x, fa.y, fa.z, fa.w, fb.x, fb.y, fb.z, fb.w};
  union { ushort_t u[8]; uint4 v; } o;
#pragma unroll
  for (int j = 0; j < 8; ++j) {
    int oc = ((i0 + j) * 1338) >> 16;
    float hv = fmaxf(fmaf(st2[oc * 2], f[j], st2[oc * 2 + 1]), 0.f);
    o.u[j] = f2bf(hv);
  }
  return o.v;
}

// ---------------- conv1: stats pass (+ bonus blocks: conv2 B', fc1 B') -----
__global__ __launch_bounds__(256) void k_conv1_stats(
    const float* __restrict__ x, const float* __restrict__ cw,
    const float* __restrict__ cb, float* __restrict__ part1,
    const float* __restrict__ cw2, ushort_t* __restrict__ wB,
    const float* __restrict__ fc1w, ushort_t* __restrict__ Bp) {
  const int t = threadIdx.x;
  if (blockIdx.x >= BATCH) {
    const int bid = blockIdx.x - BATCH;
    if (bid == 0) {
      // conv2 B': [oc][k2], k2 = sec*16+ic; sec 0..8 = Bh, 9..17 = Bl, pad 0
      for (int i = t; i < 32 * BSTR2; i += 256) {
        int oc = i / BSTR2, k = i - oc * BSTR2;
        ushort_t val = 0;
        if (k < 288) {
          int sec2 = k >> 4, ic = k & 15;
          if (sec2 < 9) {
            val = f2bf(cw2[oc * 144 + ic * 9 + sec2]);
          } else {
            float w = cw2[oc * 144 + ic * 9 + (sec2 - 9)];
            val = f2bf(w - bf2f(f2bf(w)));
          }
        }
        wB[i] = val;
      }
    } else {
      // fc1 B': Bh bf16, 896 rows x KP (only [0,1568) used; rest zero)
      const int rb = (bid - 1) * 8;
      for (int i = t; i < 8 * (KP / 8); i += 256) {
        int rr = i / (KP / 8), c = i - rr * (KP / 8);
        int n = rb + rr;
        union { ushort_t u[8]; uint4 v; } o;
        o.v = make_uint4(0, 0, 0, 0);
        if (n < 784 && c < 196) {
          const float* wp = fc1w + (size_t)n * 1568 + c * 8;
#pragma unroll
          for (int j = 0; j < 8; ++j) o.u[j] = f2bf(wp[j]);
        }
        ((uint4*)(Bp + (size_t)n * KP))[c] = o.v;
      }
    }
    return;
  }
  const int b = blockIdx.x;
  __shared__ float xs[30][33];
  __shared__ float ws[160];
  __shared__ float redS[16][28];
  __shared__ float redQ[16][28];
  for (int i = t; i < 30 * 33; i += 256) (&xs[0][0])[i] = 0.f;
  if (t < 144) ws[t] = cw[t];
  else if (t < 160) ws[t] = cb[t - 144];
  __syncthreads();
  const float* xb = x + b * 784;
  for (int i = t; i < 784; i += 256) xs[1 + i / 28][1 + (i % 28)] = xb[i];
  __syncthreads();
  for (int task = t; task < 448; task += 256) {
    const int oc = task / 28;
    const int row = task - oc * 28;
    float wk[9];
#pragma unroll
    for (int k = 0; k < 9; ++k) wk[k] = ws[oc * 9 + k];
    const float bc = ws[144 + oc];
    float A0 = xs[row][0], A1 = xs[row][1];
    float B0 = xs[row + 1][0], B1 = xs[row + 1][1];
    float C0 = xs[row + 2][0], C1 = xs[row + 2][1];
    float s = 0.f, q = 0.f;
#pragma unroll 4
    for (int xx = 0; xx < 28; ++xx) {
      float A2 = xs[row][xx + 2], B2 = xs[row + 1][xx + 2], C2 = xs[row + 2][xx + 2];
      float acc = bc;
      acc = fmaf(wk[0], A0, acc); acc = fmaf(wk[1], A1, acc); acc = fmaf(wk[2], A2, acc);
      acc = fmaf(wk[3], B0, acc); acc = fmaf(wk[4], B1, acc); acc = fmaf(wk[5], B2, acc);
      acc = fmaf(wk[6], C0, acc); acc = fmaf(wk[7], C1, acc); acc = fmaf(wk[8], C2, acc);
      s += acc; q = fmaf(acc, acc, q);
      A0 = A1; A1 = A2; B0 = B1; B1 = B2; C0 = C1; C1 = C2;
    }
    redS[oc][row] = s;
    redQ[oc][row] = q;
  }
  __syncthreads();
  if (t < 32) {
    const int c = t >> 1;
    float acc = 0.f;
    if (t & 1) {
#pragma unroll 4
      for (int r = 0; r < 28; ++r) acc += redQ[c][r];
    } else {
#pragma unroll 4
      for (int r = 0; r < 28; ++r) acc += redS[c][r];
    }
    part1[b * 32 + t] = acc;
  }
}

// ---------------- BN stats fold (both layers) -------------------------------
__global__ __launch_bounds__(256) void k_bnstat(
    const float* __restrict__ part, const float* __restrict__ g,
    const float* __restrict__ bb, float* __restrict__ stats,
    int nch, int nblk, double invN) {
  const int c = blockIdx.x;
  const int t = threadIdx.x;
  const int stride = nch * 2;
  double ls = 0.0, lq = 0.0;
  for (int i = t; i < nblk; i += 256) {
    ls += (double)part[i * stride + c * 2];
    lq += (double)part[i * stride + c * 2 + 1];
  }
#pragma unroll
  for (int off = 32; off >= 1; off >>= 1) {
    ls += __shfl_xor(ls, off, 64);
    lq += __shfl_xor(lq, off, 64);
  }
  __shared__ double rs[4], rq[4];
  if ((t & 63) == 0) { rs[t >> 6] = ls; rq[t >> 6] = lq; }
  __syncthreads();
  if (t == 0) {
    double S = rs[0] + rs[1] + rs[2] + rs[3];
    double Q = rq[0] + rq[1] + rq[2] + rq[3];
    double mean = S * invN;
    double var = Q * invN - mean * mean;
    double inv = 1.0 / sqrt(var + 1e-5);
    double sc = (double)g[c] * inv;
    stats[c * 2] = (float)sc;
    stats[c * 2 + 1] = (float)((double)bb[c] - mean * sc);
  }
}

// ---------------- conv1(fused)+conv2 via MFMA, pooled select by sign(g2) ----
// pooled layout (hv order): pooled[m][oc*49+quad]
__global__ __launch_bounds__(512, 2) void k_conv2_mfma(
    const float* __restrict__ x, const float* __restrict__ cw1,
    const float* __restrict__ cb1, const float* __restrict__ stats1,
    const ushort_t* __restrict__ wB, const float* __restrict__ cb,
    const float* __restrict__ g2, float* __restrict__ part2,
    float* __restrict__ pooled) {
  const int b0 = blockIdx.x * 2;
  const int t = threadIdx.x;
  __shared__ __align__(16) ushort_t aT[2 * AIMG];     // 50,176 B
  __shared__ __align__(16) ushort_t bS[32 * BSTR2];   // 19,968 B
  __shared__ float xs[2][30][33];                     //  7,920 B
  __shared__ float wsc[160];                          //    640 B
  __shared__ float red[2][4][64];                     //  2,048 B
  {
    uint4 z = make_uint4(0, 0, 0, 0);
    uint4* a4 = (uint4*)aT;
    for (int i = t; i < (2 * AIMG) / 8; i += 512) a4[i] = z;
    float4* xz = (float4*)&xs[0][0][0];
    if (t < 495) xz[t] = make_float4(0.f, 0.f, 0.f, 0.f);
    if (t < 160) wsc[t] = (t < 144) ? cw1[t] : cb1[t - 144];
    uint4* b4 = (uint4*)bS;
    const uint4* w4 = (const uint4*)wB;
    for (int i = t; i < (32 * BSTR2) / 8; i += 512) b4[i] = w4[i];
  }
  __syncthreads();
  {
    const float* xb = x + (size_t)b0 * 784;
    for (int i = t; i < 1568; i += 512) {
      int img = i / 784, j = i - img * 784;
      xs[img][1 + j / 28][1 + (j % 28)] = xb[img * 784 + j];
    }
  }
  __syncthreads();
  // ---- conv1 + BN1 + relu + 2x2 pool, hi/lo split -> aT ----
  if (t < 448) {
    const int img = t / 224, tt = t - img * 224;
    const int oc = tt / 14, pr = tt - oc * 14;
    float wk[9];
#pragma unroll
    for (int k = 0; k < 9; ++k) wk[k] = wsc[oc * 9 + k];
    const float bc = wsc[144 + oc];
    const float scale = stats1[oc * 2], shift = stats1[oc * 2 + 1];
    const int r0 = 2 * pr;
    float A0 = xs[img][r0][0],     A1 = xs[img][r0][1];
    float B0 = xs[img][r0 + 1][0], B1 = xs[img][r0 + 1][1];
    float C0 = xs[img][r0 + 2][0], C1 = xs[img][r0 + 2][1];
    float D0 = xs[img][r0 + 3][0], D1 = xs[img][r0 + 3][1];
    float pmax = 0.f;
#pragma unroll 4
    for (int xx = 0; xx < 28; ++xx) {
      float A2 = xs[img][r0][xx + 2], B2 = xs[img][r0 + 1][xx + 2];
      float C2 = xs[img][r0 + 2][xx + 2], D2 = xs[img][r0 + 3][xx + 2];
      float c0 = bc, c1 = bc;
      c0 = fmaf(wk[0], A0, c0); c0 = fmaf(wk[1], A1, c0); c0 = fmaf(wk[2], A2, c0);
      c0 = fmaf(wk[3], B0, c0); c0 = fmaf(wk[4], B1, c0); c0 = fmaf(wk[5], B2, c0);
      c0 = fmaf(wk[6], C0, c0); c0 = fmaf(wk[7], C1, c0); c0 = fmaf(wk[8], C2, c0);
      c1 = fmaf(wk[0], B0, c1); c1 = fmaf(wk[1], B1, c1); c1 = fmaf(wk[2], B2, c1);
      c1 = fmaf(wk[3], C0, c1); c1 = fmaf(wk[4], C1, c1); c1 = fmaf(wk[5], C2, c1);
      c1 = fmaf(wk[6], D0, c1); c1 = fmaf(wk[7], D1, c1); c1 = fmaf(wk[8], D2, c1);
      float e0 = fmaxf(fmaf(scale, c0, shift), 0.f);
      float e1 = fmaxf(fmaf(scale, c1, shift), 0.f);
      float m = fmaxf(e0, e1);
      if ((xx & 1) == 0) {
        pmax = m;
      } else {
        float pv = fmaxf(pmax, m);
        ushort_t hi = f2bf(pv);
        ushort_t lo = f2bf(pv - bf2f(hi));
        int off = img * AIMG + (pr + 1) * AROW + ((xx >> 1) + 1) * 24 + oc;
        aT[off] = hi;
        aT[off + APLANE] = lo;
      }
      A0 = A1; A1 = A2; B0 = B1; B1 = B2; C0 = C1; C1 = C2; D0 = D1; D1 = D2;
    }
  }
  __syncthreads();

  // ---- conv2 MFMA ----
  const int lane = t & 63;
  const int wv = t >> 6;
  const int img = wv >> 2, wi = wv & 3;
  const int ic0 = ((lane >> 4) & 1) * 8;
  const int hb = lane >> 5;
  const int imgbase = img * AIMG;
  int abase[4];
#pragma unroll
  for (int fi = 0; fi < 4; ++fi) {
    int f = wi + fi * 4;
    int pp = f * 16 + (lane & 15);       // quad-major row index
    int quad = pp >> 2;
    if (quad > 48) quad = 48;            // clamp: keeps A-read in-bounds
    int corner = pp & 3;
    int qy = quad / 7, qx = quad - qy * 7;
    int y = 2 * qy + (corner >> 1), xq = 2 * qx + (corner & 1);
    abase[fi] = imgbase + y * AROW + xq * 24 + ic0;  // output coords, no +1
  }
  f32x4 acc[4][2];
  {
    const float bias0 = cb[lane & 15];
    const float bias1 = cb[16 + (lane & 15)];
#pragma unroll
    for (int fi = 0; fi < 4; ++fi) {
      acc[fi][0] = (f32x4){bias0, bias0, bias0, bias0};
      acc[fi][1] = (f32x4){bias1, bias1, bias1, bias1};
    }
  }
  const int brow = (lane & 15) * BSTR2 + ic0;
#pragma unroll
  for (int kt = 0; kt < 14; ++kt) {
    int sec = 2 * kt + hb;
    int ss = sec >= 18 ? sec - 18 : (sec >= 9 ? sec - 9 : sec);
    int col16;                       // deduped B column (16-wide sections)
    if (sec >= 27) { ss = 8; col16 = 18; }      // zero pad
    else if (sec >= 18) col16 = 9 + ss;          // Bl
    else col16 = ss;                             // Bh (sec 0..17)
    int plane = (sec >= 9 && sec < 18) ? 1 : 0;
    bf16x8 bv0 = *(const bf16x8*)&bS[brow + col16 * 16];
    bf16x8 bv1 = *(const bf16x8*)&bS[brow + 16 * BSTR2 + col16 * 16];
    int dy = ss / 3, dx = ss - dy * 3;
    int doff = plane * APLANE + dy * AROW + dx * 24;
#pragma unroll
    for (int fi = 0; fi < 4; ++fi) {
      if (wi + fi * 4 < 13) {
        bf16x8 av = *(const bf16x8*)&aT[doff + abase[fi]];
        acc[fi][0] = __builtin_amdgcn_mfma_f32_16x16x32_bf16(av, bv0, acc[fi][0], 0, 0, 0);
        acc[fi][1] = __builtin_amdgcn_mfma_f32_16x16x32_bf16(av, bv1, acc[fi][1], 0, 0, 0);
      }
    }
  }
  // epilogue: in-lane 2x2 pool; keep max if g2>=0 else min (BN monotone);
  // pooled in hv order: [oc*49 + quad]
  const float gs0 = g2[lane & 15];
  const float gs1 = g2[16 + (lane & 15)];
  float s0 = 0.f, q0 = 0.f, s1 = 0.f, q1 = 0.f;
  float* pm = pooled + (size_t)(b0 + img) * 1568;
#pragma unroll
  for (int fi = 0; fi < 4; ++fi) {
    int f = wi + fi * 4;
    int quad = f * 4 + (lane >> 4);
    if (quad < 49) {
      f32x4 a0 = acc[fi][0], a1 = acc[fi][1];
#pragma unroll
      for (int r = 0; r < 4; ++r) {
        s0 += a0[r]; q0 = fmaf(a0[r], a0[r], q0);
        s1 += a1[r]; q1 = fmaf(a1[r], a1[r], q1);
      }
      float mx0 = fmaxf(fmaxf(a0[0], a0[1]), fmaxf(a0[2], a0[3]));
      float mn0 = fminf(fminf(a0[0], a0[1]), fminf(a0[2], a0[3]));
      float mx1 = fmaxf(fmaxf(a1[0], a1[1]), fmaxf(a1[2], a1[3]));
      float mn1 = fminf(fminf(a1[0], a1[1]), fminf(a1[2], a1[3]));
      pm[(lane & 15) * 49 + quad] = (gs0 >= 0.f) ? mx0 : mn0;
      pm[(16 + (lane & 15)) * 49 + quad] = (gs1 >= 0.f) ? mx1 : mn1;
    }
  }
  s0 += __shfl_xor(s0, 16, 64); s0 += __shfl_xor(s0, 32, 64);
  q0 += __shfl_xor(q0, 16, 64); q0 += __shfl_xor(q0, 32, 64);
  s1 += __shfl_xor(s1, 16, 64); s1 += __shfl_xor(s1, 32, 64);
  q1 += __shfl_xor(q1, 16, 64); q1 += __shfl_xor(q1, 32, 64);
  if (lane < 16) {
    red[img][wi][lane * 2] = s0;        red[img][wi][lane * 2 + 1] = q0;
    red[img][wi][(lane + 16) * 2] = s1; red[img][wi][(lane + 16) * 2 + 1] = q1;
  }
  __syncthreads();
  if (t < 128) {
    int im = t >> 6, c = t & 63;
    part2[(b0 + im) * 64 + c] =
        red[im][0][c] + red[im][1][c] + red[im][2][c] + red[im][3][c];
  }
}

// ---------------- fc1 bf16 MFMA GEMM: 128x128 tile, K=1568 (25 steps) -------
// A staged from pooled (hv order) + stats2 with BN2+relu+bf16 on the fly.
// Split-K=4: steps [0,6)[6,12)[12,18)[18,25). K-pad step zeroes A.
__global__ __launch_bounds__(512, 2) void k_fc1_mfma(
    const float* __restrict__ pooled, const float* __restrict__ stats2,
    const ushort_t* __restrict__ Bp, float* __restrict__ partial) {
  __shared__ ushort_t As[128 * 64];
  __shared__ ushort_t Bs[128 * 64];
  __shared__ float st2[64];
  const int t = threadIdx.x;
  if (t < 64) st2[t] = stats2[t];
  const int id = blockIdx.x;
  const int xcd = id & 7, w = id >> 3;           // w in 0..55
  const int mtl = w / 28, rem = w - mtl * 28;
  const int ks = rem / 7, nt = rem - ks * 7;
  const int mt = xcd * 2 + mtl;
  const int m0 = mt * 128, n0 = nt * 128;
  const int lane = t & 63, wid = t >> 6;
  const int wm = wid >> 2, wn = wid & 3;

  const int srow = t >> 3, sslot = t & 7;
  const int xsl = (sslot ^ (srow & 7)) << 3;
  ushort_t* awp = &As[srow * 64 + xsl];
  ushort_t* bwp = &Bs[srow * 64 + xsl];
  const float* prow0 = pooled + (size_t)(m0 + srow) * 1568;
  const float* prow1 = prow0 + (size_t)64 * 1568;
  const uint4* bgp = (const uint4*)(Bp + (size_t)(n0 + srow) * KP) + sslot;
  const int ROWOFF = 64 * (KP / 8);

  const int rbaseA = (wm * 64 + (lane & 15)) * 64;
  const int rbaseB = (wn * 32 + (lane & 15)) * 64;
  const int x0 = ((lane >> 4) ^ (lane & 7)) << 3;
  const int x1 = (((lane >> 4) + 4) ^ (lane & 7)) << 3;

  f32x4 acc[4][2];
#pragma unroll
  for (int fm = 0; fm < 4; ++fm) {
    acc[fm][0] = (f32x4){0.f, 0.f, 0.f, 0.f};
    acc[fm][1] = (f32x4){0.f, 0.f, 0.f, 0.f};
  }
  const int kt0 = (ks * 25) >> 2;           // 0, 6, 12, 18
  const int ktEnd = ((ks + 1) * 25) >> 2;   // 6, 12, 18, 25

  // prefetch step kt0
  float4 fa00 = {0, 0, 0, 0}, fa01 = fa00, fa10 = fa00, fa11 = fa00;
  uint4 cb0, cb1;
  int cc = kt0 * 64 + sslot * 8;
  bool ok = cc < 1568;
  if (ok) {
    fa00 = *(const float4*)(prow0 + cc);
    fa01 = *(const float4*)(prow0 + cc + 4);
    fa10 = *(const float4*)(prow1 + cc);
    fa11 = *(const float4*)(prow1 + cc + 4);
  }
  cb0 = bgp[kt0 * 8];
  cb1 = bgp[kt0 * 8 + ROWOFF];
  const uint4 zero4 = make_uint4(0, 0, 0, 0);
  for (int kt = kt0; kt < ktEnd; ++kt) {
    __syncthreads();
    *(uint4*)awp = ok ? xformA(fa00, fa01, cc, st2) : zero4;
    *(uint4*)(awp + 64 * 64) = ok ? xformA(fa10, fa11, cc, st2) : zero4;
    *(uint4*)bwp = cb0;
    *(uint4*)(bwp + 64 * 64) = cb1;
    __syncthreads();
    if (kt + 1 < ktEnd) {  // prefetch next step; MFMA hides latency
      cc = (kt + 1) * 64 + sslot * 8;
      ok = cc < 1568;
      if (ok) {
        fa00 = *(const float4*)(prow0 + cc);
        fa01 = *(const float4*)(prow0 + cc + 4);
        fa10 = *(const float4*)(prow1 + cc);
        fa11 = *(const float4*)(prow1 + cc + 4);
      }
      cb0 = bgp[(kt + 1) * 8];
      cb1 = bgp[(kt + 1) * 8 + ROWOFF];
    }
#pragma unroll
    for (int kh = 0; kh < 2; ++kh) {
      const int xx = kh ? x1 : x0;
      bf16x8 b0 = *(const bf16x8*)&Bs[rbaseB + xx];
      bf16x8 b1 = *(const bf16x8*)&Bs[rbaseB + 16 * 64 + xx];
#pragma unroll
      for (int fm = 0; fm < 4; ++fm) {
        bf16x8 a = *(const bf16x8*)&As[rbaseA + fm * 1024 + xx];
        acc[fm][0] = __builtin_amdgcn_mfma_f32_16x16x32_bf16(a, b0, acc[fm][0], 0, 0, 0);
        acc[fm][1] = __builtin_amdgcn_mfma_f32_16x16x32_bf16(a, b1, acc[fm][1], 0, 0, 0);
      }
    }
  }
  // C/D: col=lane&15, row=(lane>>4)*4+reg [m89]; partial [ks][2048][832]
  const int mrow0 = m0 + wm * 64 + ((lane >> 4) << 2);
  const int col0 = n0 + wn * 32 + (lane & 15);
#pragma unroll
  for (int fm = 0; fm < 4; ++fm) {
#pragma unroll
    for (int fn = 0; fn < 2; ++fn) {
      int col = col0 + fn * 16;
      if (col < 832) {
        float* pb = partial + ((size_t)ks * 2048 + mrow0 + fm * 16) * 832 + col;
#pragma unroll
        for (int r = 0; r < 4; ++r) pb[(size_t)r * 832] = acc[fm][fn][r];
      }
    }
  }
}

// ---------------- quantum gate helper (value-passed cos/sin) ----------------
template <int W>
__device__ __forceinline__ void ry_cs(float (&a)[16], int lane, float c, float s) {
  if (W < 4) {
    const int st = 1 << W;
#pragma unroll
    for (int r = 0; r < 16; ++r) {
      if (!(r & st)) {
        float lo = a[r], hi = a[r + st];
        a[r] = fmaf(c, lo, -s * hi);
        a[r + st] = fmaf(s, lo, c * hi);
      }
    }
  } else {
    const int m = 1 << (W - 4);
    const float sg = (lane & m) ? s : -s;
#pragma unroll
    for (int r = 0; r < 16; ++r) {
      float other = __shfl_xor(a[r], m, 64);
      a[r] = fmaf(c, a[r], sg * other);
    }
  }
}

#define RYCS(GC, GS)                                                  \
  {                                                                   \
    ry_cs<0>(a, lane, GC(0), GS(0)); ry_cs<1>(a, lane, GC(1), GS(1)); \
    ry_cs<2>(a, lane, GC(2), GS(2)); ry_cs<3>(a, lane, GC(3), GS(3)); \
    ry_cs<4>(a, lane, GC(4), GS(4)); ry_cs<5>(a, lane, GC(5), GS(5)); \
    ry_cs<6>(a, lane, GC(6), GS(6)); ry_cs<7>(a, lane, GC(7), GS(7)); \
    ry_cs<8>(a, lane, GC(8), GS(8)); ry_cs<9>(a, lane, GC(9), GS(9)); \
  }

// ---------------- fused tail: combine + sel + quantum + post ----------------
// Circuit algebra: encoding RY and layer-0 RY merge into a product state.
__global__ __launch_bounds__(256) void k_tail(
    const float* __restrict__ partial, const float* __restrict__ fb,
    const float* __restrict__ sw, const float* __restrict__ sb,
    const float* __restrict__ qp, const float* __restrict__ w1,
    const float* __restrict__ b1, const float* __restrict__ w2,
    const float* __restrict__ b2, float* __restrict__ out) {
  const int t = threadIdx.x;
  __shared__ __align__(16) float swL[7840];
  __shared__ float lc[30], ls[30];
  __shared__ float hbuf[4][32];
  {
    const float4* swg = (const float4*)sw;
    float4* swd = (float4*)swL;
    for (int i = t; i < 1960; i += 256) swd[i] = swg[i];
  }
  if (t < 30) {   // layers 1,2 used as (cos,sin)
    float th = 0.5f * qp[t];
    lc[t] = __cosf(th);
    ls[t] = __sinf(th);
  }
  __syncthreads();
  const int wv = t >> 6;
  const int m = blockIdx.x * 4 + wv;
  const int lane = t & 63;

  const float4* p4 = (const float4*)(partial + (size_t)m * 832);
  const size_t KSL4 = (size_t)2048 * 832 / 4;
  const float4* fb4 = (const float4*)fb;
  const float4* sw4 = (const float4*)swL;
  float acc[10];
#pragma unroll
  for (int i = 0; i < 10; ++i) acc[i] = 0.f;
  for (int c4 = lane; c4 < 196; c4 += 64) {
    float4 v0 = p4[c4];
    float4 v1 = p4[c4 + KSL4];
    float4 v2 = p4[c4 + 2 * KSL4];
    float4 v3 = p4[c4 + 3 * KSL4];
    float4 bb = fb4[c4];
    float t0 = tanh_fast(v0.x + v1.x + v2.x + v3.x + bb.x);
    float t1 = tanh_fast(v0.y + v1.y + v2.y + v3.y + bb.y);
    float t2 = tanh_fast(v0.z + v1.z + v2.z + v3.z + bb.z);
    float t3 = tanh_fast(v0.w + v1.w + v2.w + v3.w + bb.w);
#pragma unroll
    for (int i = 0; i < 10; ++i) {
      float4 w = sw4[i * 196 + c4];
      acc[i] = fmaf(t0, w.x, acc[i]);
      acc[i] = fmaf(t1, w.y, acc[i]);
      acc[i] = fmaf(t2, w.z, acc[i]);
      acc[i] = fmaf(t3, w.w, acc[i]);
    }
  }
#pragma unroll
  for (int i = 0; i < 10; ++i) acc[i] = wave_reduce_add(acc[i]) + sb[i];

  // ---- product state (encoding + layer-0 RY merged) ----
  float pc[10], psn[10];
#pragma unroll
  for (int i = 0; i < 10; ++i) {
    float h = fmaf(acc[i], 0.5f * PI_F, 0.5f * qp[i]);
    pc[i] = __cosf(h);
    psn[i] = __sinf(h);
  }
  float p01[4] = {pc[0] * pc[1], psn[0] * pc[1], pc[0] * psn[1], psn[0] * psn[1]};
  float p23[4] = {pc[2] * pc[3], psn[2] * pc[3], pc[2] * psn[3], psn[2] * psn[3]};
  float L = (lane & 1) ? psn[4] : pc[4];
  L *= ((lane >> 1) & 1) ? psn[5] : pc[5];
  L *= ((lane >> 2) & 1) ? psn[6] : pc[6];
  L *= ((lane >> 3) & 1) ? psn[7] : pc[7];
  L *= ((lane >> 4) & 1) ? psn[8] : pc[8];
  L *= ((lane >> 5) & 1) ? psn[9] : pc[9];
  float a[16];
#pragma unroll
  for (int r = 0; r < 16; ++r) a[r] = L * p01[r & 3] * p23[r >> 2];

  float czs[16];
#pragma unroll
  for (int r = 0; r < 16; ++r) {
    int idx = (lane << 4) | r;
    czs[r] = (__popc(idx & (idx >> 1)) & 1) ? -1.f : 1.f;
  }
  // CZ(L0) -> RY(L1) -> CZ(L1) -> RY(L2) -> CZ(L2)
#pragma unroll
  for (int r = 0; r < 16; ++r) a[r] *= czs[r];
#pragma unroll
  for (int layer = 1; layer < 3; ++layer) {
    const int lb = layer * 10;
#define LC(i) (lc[lb + i])
#define LS(i) (ls[lb + i])
    RYCS(LC, LS)
#undef LC
#undef LS
#pragma unroll
    for (int r = 0; r < 16; ++r) a[r] *= czs[r];
  }
  float p[16];
  float lt = 0.f;
#pragma unroll
  for (int r = 0; r < 16; ++r) { p[r] = a[r] * a[r]; lt += p[r]; }
  float z[10];
#pragma unroll
  for (int ww = 0; ww < 4; ++ww) {
    float v = 0.f;
#pragma unroll
    for (int r = 0; r < 16; ++r) v += ((r >> ww) & 1) ? -p[r] : p[r];
    z[ww] = v;
  }
#pragma unroll
  for (int ww = 4; ww < 10; ++ww) z[ww] = ((lane >> (ww - 4)) & 1) ? -lt : lt;
#pragma unroll
  for (int ww = 0; ww < 10; ++ww) z[ww] = wave_reduce_add(z[ww]);

  if (lane < 32) {
    float s = b1[lane];
#pragma unroll
    for (int i = 0; i < 10; ++i) s = fmaf(w1[lane * 10 + i], z[i], s);
    hbuf[wv][lane] = fmaxf(s, 0.f);
  }
  __syncthreads();
  if (lane < 10) {
    float s = b2[lane];
#pragma unroll
    for (int jj = 0; jj < 32; ++jj) s = fmaf(w2[lane * 32 + jj], hbuf[wv][jj], s);
    out[m * 10 + lane] = s;
  }
}

// ---------------------------------------------------------------------------
extern "C" void kernel_launch(void* const* d_in, const int* in_sizes, int n_in,
                              void* d_out, int out_size, void* d_ws, size_t ws_size,
                              hipStream_t stream) {
  (void)in_sizes; (void)n_in; (void)out_size; (void)ws_size;
  const float* x    = (const float*)d_in[0];
  const float* c1w  = (const float*)d_in[1];
  const float* c1b  = (const float*)d_in[2];
  const float* bn1g = (const float*)d_in[3];
  const float* bn1b = (const float*)d_in[4];
  const float* c2w  = (const float*)d_in[5];
  const float* c2b  = (const float*)d_in[6];
  const float* bn2g = (const float*)d_in[7];
  const float* bn2b = (const float*)d_in[8];
  const float* fc1w = (const float*)d_in[9];
  const float* fc1b = (const float*)d_in[10];
  const float* selw = (const float*)d_in[11];
  const float* selb = (const float*)d_in[12];
  const float* qpar = (const float*)d_in[13];
  const float* p1w  = (const float*)d_in[14];
  const float* p1b  = (const float*)d_in[15];
  const float* p2w  = (const float*)d_in[16];
  const float* p2b  = (const float*)d_in[17];

  // ws layout (floats) — no aliases needed (~46.6 MB total, budget 89.8 MB).
  float* ws = (float*)d_ws;
  float* pooled  = ws;                      // 3,211,264 f [2048][1568] hv order
  size_t o = 3211264;
  float* partial = ws + o; o += 6815744;    // [4][2048][832]
  ushort_t* Bp  = (ushort_t*)(ws + o); o += 1490944;  // 896*3328 ushorts
  ushort_t* wB  = (ushort_t*)(ws + o); o += 4992;     // 32*312 ushorts
  float* part1  = ws + o; o += 65536;
  float* part2  = ws + o; o += 131072;
  float* stats1 = ws + o; o += 32;
  float* stats2 = ws + o; o += 64;
  float* outp   = (float*)d_out;

  k_conv1_stats<<<BATCH + 1 + 112, 256, 0, stream>>>(x, c1w, c1b, part1, c2w,
                                                     wB, fc1w, Bp);
  k_bnstat<<<16, 256, 0, stream>>>(part1, bn1g, bn1b, stats1, 16, BATCH,
                                   1.0 / (2048.0 * 784.0));
  k_conv2_mfma<<<BATCH / 2, 512, 0, stream>>>(x, c1w, c1b, stats1, wB, c2b,
                                              bn2g, part2, pooled);
  k_bnstat<<<32, 256, 0, stream>>>(part2, bn2g, bn2b, stats2, 32, BATCH,
                                   1.0 / (2048.0 * 196.0));
  k_fc1_mfma<<<448, 512, 0, stream>>>(pooled, stats2, Bp, partial);
  k_tail<<<BATCH / 4, 256, 0, stream>>>(partial, fc1b, selw, selb, qpar,
                                        p1w, p1b, p2w, p2b, outp);
}